// Round 10
// baseline (203.253 us; speedup 1.0000x reference)
//
#include <hip/hip_runtime.h>
#include <hip/hip_bf16.h>
#include <math.h>

// Problem constants (B=2, C=256, H=W=64, Co=256, 3x3, stride1, pad1)
#define BB 2
#define CC 256
#define HH 64
#define WW 64
#define COo 256
#define HWs 4096
#define K2 9
#define CK 2304   // C*9

typedef __attribute__((ext_vector_type(4))) float floatx4;
typedef __attribute__((ext_vector_type(8))) short shortx8;   // 8 bf16
typedef __attribute__((ext_vector_type(4))) short shortx4;   // 4 bf16

// ---- workspace layout (float units) ----
#define O_OFF   0          // final offset  B*18*4096 = 147456 f
#define O_MASK  147456     // final modulator B*9*4096 = 73728 f
#define O_WBF   221184     // reg_w bf16 [co][ck] = 294912 f
#define O_WPK   516096     // convA weights [g2][kc8][tap9][nf2][lane][8] = 73728 f
#define O_P     589824     // convA fp16 partials [kc8][b2][pix4096][27]
#define O_XT    10027008   // x NHWC bf16 [b][y][x][c] = 1048576 f

__device__ __forceinline__ void gll16(const __hip_bfloat16* g, __hip_bfloat16* l) {
    __builtin_amdgcn_global_load_lds(
        (const __attribute__((address_space(1))) unsigned int*)g,
        (__attribute__((address_space(3))) unsigned int*)l, 16, 0, 0);
}

__device__ __forceinline__ short f2bf(float v) {
    __hip_bfloat16 h = __float2bfloat16(v);
    return *reinterpret_cast<short*>(&h);
}

__device__ __forceinline__ float bf2f(short s) {
    unsigned u = ((unsigned)(unsigned short)s) << 16;
    return __builtin_bit_cast(float, u);
}

// ---------------------------------------------------------------------------
// K0: pack weights (unchanged, validated R6-R8).
// ---------------------------------------------------------------------------
__global__ __launch_bounds__(256) void pack_kernel(
    const float* __restrict__ reg_w,
    const float* __restrict__ off_w,
    const float* __restrict__ mod_w,
    __hip_bfloat16* __restrict__ Wbf,
    __hip_bfloat16* __restrict__ Wpk)
{
    int idx = blockIdx.x * 256 + threadIdx.x;
    if (idx < CK * COo) {
        Wbf[idx] = __float2bfloat16(reg_w[idx]);
    }
    if (idx < 147456) {
        int g    = idx / 73728;
        int rem  = idx % 73728;
        int kc   = rem / 9216;
        int r2   = rem % 9216;
        int tap  = r2 / 1024;
        int r3   = r2 & 1023;
        int nf   = r3 >> 9;
        int r4   = r3 & 511;
        int lane = r4 >> 3;
        int j    = r4 & 7;
        int c    = kc * 32 + (lane >> 4) * 8 + j;
        int n    = nf * 16 + (lane & 15);
        float v = 0.f;
        if (g == 0) { if (n < 18) v = off_w[((size_t)n * CC + c) * 9 + tap]; }
        else        { if (n < 9)  v = mod_w[((size_t)n * CC + c) * 9 + tap]; }
        Wpk[idx] = __float2bfloat16(v);
    }
}

// ---------------------------------------------------------------------------
// K0b: x (NCHW fp32) -> xT (NHWC bf16). (unchanged, validated R7-R8)
// ---------------------------------------------------------------------------
__global__ __launch_bounds__(256) void transpose_kernel(
    const float* __restrict__ x,
    __hip_bfloat16* __restrict__ xT)
{
    int blk = blockIdx.x;            // ((b*64 + y)*8 + oc)
    int oc = blk & 7;
    int y  = (blk >> 3) & 63;
    int b  = blk >> 9;
    int t = threadIdx.x;
    int wo = t & 63;
    int cg = t >> 6;
    int c0 = oc * 32 + cg * 8;
    const float* src = x + ((size_t)(b * CC + c0) * HH + y) * WW + wo;
    shortx8 pk;
#pragma unroll
    for (int j = 0; j < 8; ++j) pk[j] = f2bf(src[(size_t)j * HWs]);
    *(shortx8*)(xT + ((size_t)b * 4096 + y * 64 + wo) * 256 + c0) = pk;
}

// ---------------------------------------------------------------------------
// K1: offset + modulator convs via MFMA (unchanged, validated R7-R8).
// ---------------------------------------------------------------------------
__global__ __launch_bounds__(256) void convA_kernel(
    const float* __restrict__ x,
    const float* __restrict__ residual,
    const __hip_bfloat16* __restrict__ Wpk,
    _Float16* __restrict__ P)
{
    int blk = blockIdx.x;
    int rt = blk & 7;
    int kc = (blk >> 3) & 7;
    int g  = (blk >> 6) & 1;
    int b  = blk >> 7;
    int t = threadIdx.x;
    int lane = t & 63;
    int w = t >> 6;
    int ln = lane & 15;
    int quad = lane >> 4;

    __shared__ __hip_bfloat16 Xs[4 * 640 * 8];   // [chunk][row*64+col][8] (40 KB)
    __shared__ __hip_bfloat16 Wl[9216];          // weight slice (18 KB)

    const float* src = (g ? x : residual) + ((size_t)b * CC + kc * 32) * HWs;
    const __hip_bfloat16* wsrc = Wpk + (size_t)(g * 8 + kc) * 9216;

#pragma unroll
    for (int i = 0; i < 4; ++i) {
        int cid = i * 256 + t;
        gll16(wsrc + cid * 8, &Wl[cid * 8]);
    }
    if (t < 128) {
        int cid = 1024 + t;
        gll16(wsrc + cid * 8, &Wl[cid * 8]);
    }

    int col = t & 63;
    int q = t >> 6;
#pragma unroll
    for (int i = 0; i < 10; ++i) {
        int p = q * 10 + i;            // 0..39
        int row = p >> 2;              // 0..9
        int cgp = p & 3;               // c-chunk of 8
        int rimg = rt * 8 + row - 1;
        bool rv = (rimg >= 0) && (rimg < HH);
        const float* sp = src + (size_t)(cgp * 8) * HWs + rimg * WW + col;
        shortx8 pk;
#pragma unroll
        for (int jc = 0; jc < 8; ++jc)
            pk[jc] = f2bf(rv ? sp[(size_t)jc * HWs] : 0.f);
        *(shortx8*)&Xs[(cgp * 640 + row * 64 + col) * 8] = pk;
    }
    __syncthreads();

    floatx4 acc[8][2];
#pragma unroll
    for (int mf = 0; mf < 8; ++mf) {
        acc[mf][0] = (floatx4){0.f, 0.f, 0.f, 0.f};
        acc[mf][1] = (floatx4){0.f, 0.f, 0.f, 0.f};
    }

#pragma unroll
    for (int tap = 0; tap < 9; ++tap) {
        int ky = tap / 3;
        int kx = tap % 3;
        const __hip_bfloat16* wp = &Wl[((tap * 2) * 64 + lane) * 8];
        shortx8 b0 = *(const shortx8*)wp;
        shortx8 b1 = *(const shortx8*)(wp + 512);
#pragma unroll
        for (int mf = 0; mf < 8; ++mf) {
            int p = (w * 8 + mf) * 16 + ln;
            int row_local = p >> 6;
            int colp = p & 63;
            int colA = colp + kx - 1;
            bool cv = (colA >= 0) && (colA < WW);
            int colC = cv ? colA : 0;
            shortx8 afr = *(const shortx8*)
                &Xs[(quad * 640 + (row_local + ky) * 64 + colC) * 8];
            if (!cv) {
                shortx8 zf = {0,0,0,0,0,0,0,0};
                afr = zf;
            }
            acc[mf][0] = __builtin_amdgcn_mfma_f32_16x16x32_bf16(afr, b0, acc[mf][0], 0, 0, 0);
            acc[mf][1] = __builtin_amdgcn_mfma_f32_16x16x32_bf16(afr, b1, acc[mf][1], 0, 0, 0);
        }
    }

#pragma unroll
    for (int nf = 0; nf < 2; ++nf) {
        int n = nf * 16 + ln;
        bool valid = g ? (n < 9) : (n < 18);
        int n_eff = g ? (18 + n) : n;
        if (valid) {
#pragma unroll
            for (int mf = 0; mf < 8; ++mf) {
#pragma unroll
                for (int i2 = 0; i2 < 4; ++i2) {
                    int p = (w * 8 + mf) * 16 + quad * 4 + i2;
                    int pix = rt * 512 + p;
                    P[((size_t)(kc * 2 + b) * 4096 + pix) * 27 + n_eff] =
                        (_Float16)acc[mf][nf][i2];
                }
            }
        }
    }
}

// ---------------------------------------------------------------------------
// K1b: reduce 8 kc-partials + bias (+2*sigmoid) -> final off/mask. (unchanged)
// ---------------------------------------------------------------------------
__global__ __launch_bounds__(256) void reduce_kernel(
    const _Float16* __restrict__ P,
    const float* __restrict__ off_b,
    const float* __restrict__ mod_b,
    float* __restrict__ off_out,
    float* __restrict__ mask_out)
{
    int id = blockIdx.x * 256 + threadIdx.x;
    if (id >= 2 * 4096 * 27) return;
    int n = id % 27;
    int pb = id / 27;
    int pix = pb & 4095;
    int b = pb >> 12;
    float s = 0.f;
#pragma unroll
    for (int kcc = 0; kcc < 8; ++kcc)
        s += (float)P[((size_t)(kcc * 2 + b) * 4096 + pix) * 27 + n];
    if (n < 18) {
        off_out[((size_t)b * 18 + n) * 4096 + pix] = s + off_b[n];
    } else {
        float z = s + mod_b[n - 18];
        mask_out[((size_t)b * 9 + (n - 18)) * 4096 + pix] = 2.f / (1.f + __expf(-z));
    }
}

// ---------------------------------------------------------------------------
// K2: FUSED gather + GEMM, conservative B path (regs + ds_write, NO DMA).
// grid = 256: blk = b*128 + pt. Block computes C[32 pix][256 co], K=2304
// as 8 chunks of 288 (32 ch x 9 taps). Per chunk: gather A-tile 32x296-pitch
// into LDS, then 9 BK=32 steps; B staged from registers each step (validated
// R2/R3 pattern), next-step B global prefetch overlaps MFMA.
// Bank audits: Bs write 16B-stride even; As/Bs b128 reads all 32 banks x8
// (structural min); gather b64 writes 4/bank (min). LDS 53.8 KB -> 2 blk/CU.
// ---------------------------------------------------------------------------
__global__ __launch_bounds__(256) void fused_kernel(
    const __hip_bfloat16* __restrict__ xT,
    const float* __restrict__ off,
    const float* __restrict__ mask,
    const __hip_bfloat16* __restrict__ Wbf,
    float* __restrict__ out)
{
    int blk = blockIdx.x;         // b*128 + pt
    int pt = blk & 127;
    int b  = blk >> 7;
    int t  = threadIdx.x;
    int lane = t & 63;
    int w    = t >> 6;
    int quad = lane >> 4;
    int ln   = lane & 15;

    __shared__ int   s_idx[4][K2][32];            // 4.6 KB
    __shared__ float s_w  [4][K2][32];            // 4.6 KB
    __shared__ __hip_bfloat16 As[32 * 296];       // 18.9 KB, pitch 296
    __shared__ __hip_bfloat16 Bs[4 * 256 * 8];    // 16 KB, [sub][co][8]
    __shared__ float s_out[4][16 * 36];           // 9.2 KB per-wave epilogue

    // ---- phase 0: bilinear precompute for 32 pixels x 9 taps ----
    for (int u = t; u < 288; u += 256) {
        int pp = u & 31;
        int k = u >> 5;
        int hw = pt * 32 + pp;
        int ho = hw >> 6, wo = hw & 63;
        float dy = off[((size_t)b * 18 + 2 * k) * HWs + hw];
        float dx = off[((size_t)b * 18 + 2 * k + 1) * HWs + hw];
        float m  = mask[((size_t)b * 9 + k) * HWs + hw];
        float py = (float)(ho - 1 + k / 3) + dy;
        float px = (float)(wo - 1 + k % 3) + dx;
        float y0f = floorf(py), x0f = floorf(px);
        float wy1 = py - y0f, wx1 = px - x0f;
        float wy0 = 1.f - wy1, wx0 = 1.f - wx1;
        int y0 = (int)y0f, x0 = (int)x0f;
#pragma unroll
        for (int j = 0; j < 4; ++j) {
            int yy = y0 + (j >> 1);
            int xx = x0 + (j & 1);
            float wj = ((j == 0) ? wy0 * wx0 :
                        (j == 1) ? wy0 * wx1 :
                        (j == 2) ? wy1 * wx0 : wy1 * wx1) * m;
            bool valid = (yy >= 0) && (yy < HH) && (xx >= 0) && (xx < WW);
            s_idx[j][k][pp] = valid ? (yy * WW + xx) : 0;
            s_w  [j][k][pp] = valid ? wj : 0.f;
        }
    }

    // ---- B register prefetch for it=0: thread owns co row of Wbf ----
    int coB = w * 64 + lane;
    const __hip_bfloat16* gB0 = Wbf + (size_t)coB * CK;
    shortx8 breg[4];
#pragma unroll
    for (int i = 0; i < 4; ++i)
        breg[i] = *(const shortx8*)(gB0 + i * 8);

    floatx4 acc[2][4];
#pragma unroll
    for (int mf = 0; mf < 2; ++mf)
#pragma unroll
        for (int nf = 0; nf < 4; ++nf) acc[mf][nf] = (floatx4){0.f, 0.f, 0.f, 0.f};

    const __hip_bfloat16* xbase = xT + (size_t)b * 4096 * 256;
    int p  = t & 31;              // gather pixel
    int cg = t >> 5;              // gather channel group (0..7, 4 ch each)

    for (int cc = 0; cc < 8; ++cc) {
        __syncthreads();          // prior As reads done; s_idx ready (cc==0)

        // ---- gather chunk cc: 4 ch x 9 taps = 36 contiguous A elems ----
        int cbase = cc * 32 + cg * 4;
        shortx4 outv[9];
#pragma unroll
        for (int k = 0; k < K2; ++k) {
            int   i0 = s_idx[0][k][p], i1 = s_idx[1][k][p];
            int   i2 = s_idx[2][k][p], i3 = s_idx[3][k][p];
            float w0 = s_w[0][k][p], w1 = s_w[1][k][p];
            float w2 = s_w[2][k][p], w3 = s_w[3][k][p];
            shortx4 c0 = *(const shortx4*)(xbase + (size_t)i0 * 256 + cbase);
            shortx4 c1 = *(const shortx4*)(xbase + (size_t)i1 * 256 + cbase);
            shortx4 c2 = *(const shortx4*)(xbase + (size_t)i2 * 256 + cbase);
            shortx4 c3 = *(const shortx4*)(xbase + (size_t)i3 * 256 + cbase);
#pragma unroll
            for (int j = 0; j < 4; ++j) {
                float v = w0 * bf2f(c0[j]) + w1 * bf2f(c1[j])
                        + w2 * bf2f(c2[j]) + w3 * bf2f(c3[j]);
                int idx = j * 9 + k;          // ck_local = c_local*9 + tap
                outv[idx >> 2][idx & 3] = f2bf(v);
            }
        }
        {
            __hip_bfloat16* arow = &As[p * 296 + cg * 36];
#pragma unroll
            for (int m2 = 0; m2 < 9; ++m2)
                *(shortx4*)(arow + m2 * 4) = outv[m2];
        }

        // ---- 9 BK=32 MFMA steps; B staged from regs each step ----
        for (int kt = 0; kt < 9; ++kt) {
            __syncthreads();      // As ready (kt==0); prior Bs reads done
#pragma unroll
            for (int i = 0; i < 4; ++i)
                *(shortx8*)&Bs[i * 2048 + coB * 8] = breg[i];
            __syncthreads();      // Bs ready
            int it = cc * 9 + kt;
            if (it + 1 < 72) {    // prefetch next B slice (overlaps MFMA)
                int kofs = (it + 1) * 32;
#pragma unroll
                for (int i = 0; i < 4; ++i)
                    breg[i] = *(const shortx8*)(gB0 + kofs + i * 8);
            }
            shortx8 af[2], bfv[4];
#pragma unroll
            for (int mf = 0; mf < 2; ++mf)
                af[mf] = *(const shortx8*)
                    &As[(mf * 16 + ln) * 296 + kt * 32 + quad * 8];
#pragma unroll
            for (int nf = 0; nf < 4; ++nf)
                bfv[nf] = *(const shortx8*)
                    &Bs[quad * 2048 + (w * 64 + nf * 16 + ln) * 8];
#pragma unroll
            for (int mf = 0; mf < 2; ++mf)
#pragma unroll
                for (int nf = 0; nf < 4; ++nf)
                    acc[mf][nf] = __builtin_amdgcn_mfma_f32_16x16x32_bf16(
                        af[mf], bfv[nf], acc[mf][nf], 0, 0, 0);
        }
    }

    // ---- epilogue: per-wave LDS transpose, coalesced NCHW stores ----
    int pix0 = pt * 32;
    float* sw = &s_out[w][0];
    int cl  = lane >> 2;          // 0..15 (co within frag)
    int seg = lane & 3;           // 0..3  (8-pixel segment)
#pragma unroll
    for (int nf = 0; nf < 4; ++nf) {
        *(floatx4*)&sw[ln * 36 + quad * 4]      = acc[0][nf];
        *(floatx4*)&sw[ln * 36 + 16 + quad * 4] = acc[1][nf];
        floatx4 v0 = *(const floatx4*)&sw[cl * 36 + seg * 8];
        floatx4 v1 = *(const floatx4*)&sw[cl * 36 + seg * 8 + 4];
        int co = w * 64 + nf * 16 + cl;
        float* orow = out + ((size_t)(b * COo + co) << 12) + pix0 + seg * 8;
        *(floatx4*)&orow[0] = v0;
        *(floatx4*)&orow[4] = v1;
    }
}

// ---------------------------------------------------------------------------
extern "C" void kernel_launch(void* const* d_in, const int* in_sizes, int n_in,
                              void* d_out, int out_size, void* d_ws, size_t ws_size,
                              hipStream_t stream)
{
    const float* x     = (const float*)d_in[0];
    const float* resid = (const float*)d_in[1];
    const float* off_w = (const float*)d_in[2];
    const float* off_b = (const float*)d_in[3];
    const float* mod_w = (const float*)d_in[4];
    const float* mod_b = (const float*)d_in[5];
    const float* reg_w = (const float*)d_in[6];
    float* out = (float*)d_out;

    float* ws = (float*)d_ws;
    float* off_buf   = ws + O_OFF;
    float* mask_buf  = ws + O_MASK;
    __hip_bfloat16* Wbf  = (__hip_bfloat16*)(ws + O_WBF);
    __hip_bfloat16* Wpk  = (__hip_bfloat16*)(ws + O_WPK);
    _Float16* Pbuf       = (_Float16*)(ws + O_P);
    __hip_bfloat16* xT   = (__hip_bfloat16*)(ws + O_XT);

    pack_kernel<<<(CK * COo + 255) / 256, 256, 0, stream>>>(reg_w, off_w, mod_w, Wbf, Wpk);

    transpose_kernel<<<BB * HH * 8, 256, 0, stream>>>(x, xT);

    convA_kernel<<<256, 256, 0, stream>>>(x, resid, Wpk, Pbuf);

    reduce_kernel<<<864, 256, 0, stream>>>(Pbuf, off_b, mod_b, off_buf, mask_buf);

    fused_kernel<<<BB * 128, 256, 0, stream>>>(xT, off_buf, mask_buf, Wbf, out);
}

// Round 11
// 170.987 us; speedup vs baseline: 1.1887x; 1.1887x over previous
//
#include <hip/hip_runtime.h>
#include <hip/hip_bf16.h>
#include <math.h>

// Problem constants (B=2, C=256, H=W=64, Co=256, 3x3, stride1, pad1)
#define BB 2
#define CC 256
#define HH 64
#define WW 64
#define COo 256
#define HWs 4096
#define K2 9
#define CK 2304   // C*9

typedef __attribute__((ext_vector_type(4))) float floatx4;
typedef __attribute__((ext_vector_type(8))) short shortx8;   // 8 bf16

// ---- workspace layout (float units) ----
#define O_OFF   0          // final offset  B*18*4096 = 147456 f
#define O_MASK  147456     // final modulator B*9*4096 = 73728 f
#define O_WBF   221184     // reg_w bf16 [co][ck] = 294912 f
#define O_WPK   516096     // convA weights [g2][kc8][tap9][nf2][lane][8] = 73728 f
#define O_A     589824     // A matrix bf16 [pix 8192][ck 2304] = 9437184 f
#define O_XT    10027008   // x NHWC bf16 [b][y][x][c] = 1048576 f
#define O_RT    11075584   // residual NHWC bf16 = 1048576 f
// total = 12,124,160 floats = 48.5 MB

__device__ __forceinline__ void gll16(const __hip_bfloat16* g, __hip_bfloat16* l) {
    __builtin_amdgcn_global_load_lds(
        (const __attribute__((address_space(1))) unsigned int*)g,
        (__attribute__((address_space(3))) unsigned int*)l, 16, 0, 0);
}

__device__ __forceinline__ short f2bf(float v) {
    __hip_bfloat16 h = __float2bfloat16(v);
    return *reinterpret_cast<short*>(&h);
}

__device__ __forceinline__ float bf2f(short s) {
    unsigned u = ((unsigned)(unsigned short)s) << 16;
    return __builtin_bit_cast(float, u);
}

// ---------------------------------------------------------------------------
// K0: pack weights (unchanged, validated R6-R10).
//  Wbf[co*2304+ck] = bf16(reg_w)
//  Wpk: [g2][kc8][tap9][nf2][lane64][j8], c = kc*32+(lane>>4)*8+j,
//       n = nf*16+(lane&15); g=0: off_w[n][c][tap], g=1: mod_w
// ---------------------------------------------------------------------------
__global__ __launch_bounds__(256) void pack_kernel(
    const float* __restrict__ reg_w,
    const float* __restrict__ off_w,
    const float* __restrict__ mod_w,
    __hip_bfloat16* __restrict__ Wbf,
    __hip_bfloat16* __restrict__ Wpk)
{
    int idx = blockIdx.x * 256 + threadIdx.x;
    if (idx < CK * COo) {
        Wbf[idx] = __float2bfloat16(reg_w[idx]);
    }
    if (idx < 147456) {
        int g    = idx / 73728;
        int rem  = idx % 73728;
        int kc   = rem / 9216;
        int r2   = rem % 9216;
        int tap  = r2 / 1024;
        int r3   = r2 & 1023;
        int nf   = r3 >> 9;
        int r4   = r3 & 511;
        int lane = r4 >> 3;
        int j    = r4 & 7;
        int c    = kc * 32 + (lane >> 4) * 8 + j;
        int n    = nf * 16 + (lane & 15);
        float v = 0.f;
        if (g == 0) { if (n < 18) v = off_w[((size_t)n * CC + c) * 9 + tap]; }
        else        { if (n < 9)  v = mod_w[((size_t)n * CC + c) * 9 + tap]; }
        Wpk[idx] = __float2bfloat16(v);
    }
}

// ---------------------------------------------------------------------------
// K0b: {x, residual} (NCHW fp32) -> {xT, resT} (NHWC bf16). grid = 2048.
// ---------------------------------------------------------------------------
__global__ __launch_bounds__(256) void transpose_kernel(
    const float* __restrict__ x,
    const float* __restrict__ residual,
    __hip_bfloat16* __restrict__ xT,
    __hip_bfloat16* __restrict__ resT)
{
    int blk = blockIdx.x;
    int sel = blk >> 10;             // 0 = x, 1 = residual
    int bk  = blk & 1023;            // ((b*64 + y)*8 + oc)
    int oc = bk & 7;
    int y  = (bk >> 3) & 63;
    int b  = bk >> 9;
    int t = threadIdx.x;
    int wo = t & 63;
    int cg = t >> 6;
    int c0 = oc * 32 + cg * 8;
    const float* src = (sel ? residual : x)
                       + ((size_t)(b * CC + c0) * HH + y) * WW + wo;
    shortx8 pk;
#pragma unroll
    for (int j = 0; j < 8; ++j) pk[j] = f2bf(src[(size_t)j * HWs]);
    __hip_bfloat16* dst = sel ? resT : xT;
    *(shortx8*)(dst + ((size_t)b * 4096 + y * 64 + wo) * 256 + c0) = pk;
}

// ---------------------------------------------------------------------------
// K1: DIRECT offset+modulator conv, no LDS, no barriers. grid = 512
// (b2 x g2 x 128 tiles of 32 pix), block 128 = 2 waves, wave = 16 pixels.
// Per wave: 72 iters (9 taps x 8 kc) of {1 A-frag 16B load from xT/resT at
// the tap-shifted pixel (edge-masked), 2 coalesced B-frag loads from Wpk,
// 2 MFMA}. Full K per wave -> writes final off/mask with bias+sigmoid.
// ---------------------------------------------------------------------------
__global__ __launch_bounds__(128) void convA2_kernel(
    const __hip_bfloat16* __restrict__ xT,
    const __hip_bfloat16* __restrict__ resT,
    const __hip_bfloat16* __restrict__ Wpk,
    const float* __restrict__ off_b,
    const float* __restrict__ mod_b,
    float* __restrict__ off_out,
    float* __restrict__ mask_out)
{
    int blk = blockIdx.x;
    int tile = blk & 127;
    int g = (blk >> 7) & 1;
    int b = blk >> 8;
    int t = threadIdx.x;
    int lane = t & 63;
    int w = t >> 6;                  // 0/1
    int ln = lane & 15;
    int quad = lane >> 4;

    // g=0: offset conv on residual; g=1: modulator conv on x
    const __hip_bfloat16* src = (g ? xT : resT) + (size_t)b * 4096 * 256;
    const __hip_bfloat16* wg  = Wpk + (size_t)g * 73728;

    int pix = tile * 32 + w * 16 + ln;   // this lane's A-row (pixel)
    int ho = pix >> 6, wo = pix & 63;

    floatx4 acc0 = (floatx4){0.f, 0.f, 0.f, 0.f};
    floatx4 acc1 = (floatx4){0.f, 0.f, 0.f, 0.f};

#pragma unroll
    for (int tap = 0; tap < 9; ++tap) {
        int ky = tap / 3, kx = tap % 3;
        int r  = ho + ky - 1;
        int cx = wo + kx - 1;
        bool v = (r >= 0) && (r < HH) && (cx >= 0) && (cx < WW);
        int hw = v ? (r * WW + cx) : 0;
        const __hip_bfloat16* abase = src + (size_t)hw * 256 + quad * 8;
        const __hip_bfloat16* wbase = wg + (size_t)tap * 1024 + lane * 8;
#pragma unroll
        for (int kc = 0; kc < 8; ++kc) {
            shortx8 af = *(const shortx8*)(abase + kc * 32);
            if (!v) {
                shortx8 zf = {0,0,0,0,0,0,0,0};
                af = zf;
            }
            shortx8 b0 = *(const shortx8*)(wbase + (size_t)kc * 9216);
            shortx8 b1 = *(const shortx8*)(wbase + (size_t)kc * 9216 + 512);
            acc0 = __builtin_amdgcn_mfma_f32_16x16x32_bf16(af, b0, acc0, 0, 0, 0);
            acc1 = __builtin_amdgcn_mfma_f32_16x16x32_bf16(af, b1, acc1, 0, 0, 0);
        }
    }

    // epilogue: C/D col=lane&15 (=n), row=quad*4+reg (=pixel within 16)
#pragma unroll
    for (int nf = 0; nf < 2; ++nf) {
        floatx4 a = nf ? acc1 : acc0;
        int n = nf * 16 + ln;
#pragma unroll
        for (int i2 = 0; i2 < 4; ++i2) {
            int p = tile * 32 + w * 16 + quad * 4 + i2;
            if (g == 0) {
                if (n < 18)
                    off_out[((size_t)b * 18 + n) * HWs + p] = a[i2] + off_b[n];
            } else {
                if (n < 9) {
                    float z = a[i2] + mod_b[n];
                    mask_out[((size_t)b * 9 + n) * HWs + p] =
                        2.f / (1.f + __expf(-z));
                }
            }
        }
    }
}

// ---------------------------------------------------------------------------
// K2: deformable gather -> bf16 A [pix][ck]. (verbatim from validated R8)
// ---------------------------------------------------------------------------
__global__ __launch_bounds__(256) void gather_kernel(
    const __hip_bfloat16* __restrict__ xT,
    const float* __restrict__ off,
    const float* __restrict__ mask,
    __hip_bfloat16* __restrict__ A)
{
    int blk = blockIdx.x;            // ((b*64 + ho)*8 + cc)
    int cc = blk & 7;
    int ho = (blk >> 3) & 63;
    int b  = blk >> 9;
    int t  = threadIdx.x;
    int wo = t & 63;
    int cg = t >> 6;

    __shared__ int   s_idx[4][K2][64];
    __shared__ float s_w  [4][K2][64];

    for (int u = t; u < K2 * 64; u += 256) {
        int k = u >> 6;
        int wv = u & 63;
        float dy = off[((((size_t)b * 18 + 2 * k    ) * HH + ho) << 6) + wv];
        float dx = off[((((size_t)b * 18 + 2 * k + 1) * HH + ho) << 6) + wv];
        float m  = mask[((((size_t)b * 9 + k) * HH + ho) << 6) + wv];
        float py = (float)(ho - 1 + k / 3) + dy;
        float px = (float)(wv - 1 + k % 3) + dx;
        float y0f = floorf(py), x0f = floorf(px);
        float wy1 = py - y0f, wx1 = px - x0f;
        float wy0 = 1.f - wy1, wx0 = 1.f - wx1;
        int y0 = (int)y0f, x0 = (int)x0f;
#pragma unroll
        for (int j = 0; j < 4; ++j) {
            int yy = y0 + (j >> 1);
            int xx = x0 + (j & 1);
            float wj = ((j == 0) ? wy0 * wx0 :
                        (j == 1) ? wy0 * wx1 :
                        (j == 2) ? wy1 * wx0 : wy1 * wx1) * m;
            bool valid = (yy >= 0) && (yy < HH) && (xx >= 0) && (xx < WW);
            s_idx[j][k][wv] = valid ? (yy * WW + xx) : 0;
            s_w  [j][k][wv] = valid ? wj : 0.f;
        }
    }
    __syncthreads();

    const __hip_bfloat16* xb = xT + (size_t)b * 4096 * 256 + cc * 32 + cg * 8;

    shortx8 outv[9];
#pragma unroll
    for (int k = 0; k < K2; ++k) {
        int   i0 = s_idx[0][k][wo], i1 = s_idx[1][k][wo];
        int   i2 = s_idx[2][k][wo], i3 = s_idx[3][k][wo];
        float w0 = s_w[0][k][wo], w1 = s_w[1][k][wo];
        float w2 = s_w[2][k][wo], w3 = s_w[3][k][wo];
        shortx8 c0 = *(const shortx8*)(xb + (size_t)i0 * 256);
        shortx8 c1 = *(const shortx8*)(xb + (size_t)i1 * 256);
        shortx8 c2 = *(const shortx8*)(xb + (size_t)i2 * 256);
        shortx8 c3 = *(const shortx8*)(xb + (size_t)i3 * 256);
#pragma unroll
        for (int j = 0; j < 8; ++j) {
            float v = w0 * bf2f(c0[j]) + w1 * bf2f(c1[j])
                    + w2 * bf2f(c2[j]) + w3 * bf2f(c3[j]);
            int idx = j * 9 + k;
            outv[idx >> 3][idx & 7] = f2bf(v);
        }
    }

    __hip_bfloat16* arow = A + (size_t)((b * 64 + ho) * 64 + wo) * CK
                             + cc * 288 + cg * 72;
#pragma unroll
    for (int m = 0; m < 9; ++m)
        *(shortx8*)(arow + m * 8) = outv[m];
}

// ---------------------------------------------------------------------------
// K3: bf16 MFMA GEMM. (verbatim from validated R8: 64Mx128N, BK=64, dbuf DMA)
// ---------------------------------------------------------------------------
__global__ __launch_bounds__(256) void gemm_kernel(
    const __hip_bfloat16* __restrict__ A,
    const __hip_bfloat16* __restrict__ Wbf,
    float* __restrict__ out)
{
    int blk = blockIdx.x;
    int nt = blk & 1;
    int mt = blk >> 1;              // 0..127
    int t  = threadIdx.x;
    int lane = t & 63;
    int w    = t >> 6;
    int quad = lane >> 4;
    int ln   = lane & 15;
    int wm = w & 1;                 // M half (32 rows)
    int wn = w >> 1;                // N half (64 cols)

    __shared__ __hip_bfloat16 As[2][64 * 64];    // 2 x 8 KB
    __shared__ __hip_bfloat16 Bs[2][128 * 64];   // 2 x 16 KB
    __shared__ float s_out[4][16 * 40];          // per-wave epilogue (10 KB)

    int lr8 = lane >> 3;            // 0..7 (staging row within wave's 8)
    int sub = lane & 7;             // 16B slot within 128B row
    int chk = sub ^ lr8;            // global k-chunk this lane fetches

    const __hip_bfloat16* gA = A + (size_t)(mt * 64 + w * 8 + lr8) * CK + chk * 8;
    const __hip_bfloat16* gB = Wbf + (size_t)(nt * 128 + w * 8 + lr8) * CK + chk * 8;
    int lofA = w * 512;             // elements
    int lofB = w * 512;

    floatx4 acc[2][4];
#pragma unroll
    for (int mf = 0; mf < 2; ++mf)
#pragma unroll
        for (int nf = 0; nf < 4; ++nf) acc[mf][nf] = (floatx4){0.f, 0.f, 0.f, 0.f};

#pragma unroll
    for (int h = 0; h < 2; ++h)
        gll16(gA + (size_t)(h * 32) * CK, &As[0][lofA + h * 2048]);
#pragma unroll
    for (int h = 0; h < 4; ++h)
        gll16(gB + (size_t)(h * 32) * CK, &Bs[0][lofB + h * 2048]);

    int swz = ln & 7;               // read-slot XOR key

    for (int kt = 0; kt < 36; ++kt) {
        int cur = kt & 1;
        int nxt = cur ^ 1;
        __syncthreads();                      // buf[cur] staging complete
        if (kt + 1 < 36) {
            int ko = (kt + 1) * 64;
#pragma unroll
            for (int h = 0; h < 2; ++h)
                gll16(gA + (size_t)(h * 32) * CK + ko, &As[nxt][lofA + h * 2048]);
#pragma unroll
            for (int h = 0; h < 4; ++h)
                gll16(gB + (size_t)(h * 32) * CK + ko, &Bs[nxt][lofB + h * 2048]);
        }
#pragma unroll
        for (int kh = 0; kh < 2; ++kh) {
            int slot = ((kh * 4 + quad) ^ swz) * 8;
            shortx8 af[2], bf[4];
#pragma unroll
            for (int mf = 0; mf < 2; ++mf)
                af[mf] = *(const shortx8*)
                    &As[cur][(wm * 32 + mf * 16 + ln) * 64 + slot];
#pragma unroll
            for (int nf = 0; nf < 4; ++nf)
                bf[nf] = *(const shortx8*)
                    &Bs[cur][(wn * 64 + nf * 16 + ln) * 64 + slot];
#pragma unroll
            for (int mf = 0; mf < 2; ++mf)
#pragma unroll
                for (int nf = 0; nf < 4; ++nf)
                    acc[mf][nf] = __builtin_amdgcn_mfma_f32_16x16x32_bf16(
                        af[mf], bf[nf], acc[mf][nf], 0, 0, 0);
        }
    }

    int bb = mt >> 6;
    int hw0 = (mt & 63) * 64 + wm * 32;
    float* sw = &s_out[w][0];
    int co_l = lane >> 2;
    int seg  = lane & 3;
#pragma unroll
    for (int nf = 0; nf < 4; ++nf) {
        *(floatx4*)&sw[ln * 40 + quad * 4]      = acc[0][nf];
        *(floatx4*)&sw[ln * 40 + 16 + quad * 4] = acc[1][nf];
        floatx4 v0 = *(const floatx4*)&sw[co_l * 40 + seg * 4];
        floatx4 v1 = *(const floatx4*)&sw[co_l * 40 + 16 + seg * 4];
        int co = nt * 128 + wn * 64 + nf * 16 + co_l;
        float* orow = out + ((size_t)(bb * COo + co) << 12) + hw0;
        *(floatx4*)&orow[seg * 4]      = v0;
        *(floatx4*)&orow[16 + seg * 4] = v1;
    }
}

// ---------------------------------------------------------------------------
extern "C" void kernel_launch(void* const* d_in, const int* in_sizes, int n_in,
                              void* d_out, int out_size, void* d_ws, size_t ws_size,
                              hipStream_t stream)
{
    const float* x     = (const float*)d_in[0];
    const float* resid = (const float*)d_in[1];
    const float* off_w = (const float*)d_in[2];
    const float* off_b = (const float*)d_in[3];
    const float* mod_w = (const float*)d_in[4];
    const float* mod_b = (const float*)d_in[5];
    const float* reg_w = (const float*)d_in[6];
    float* out = (float*)d_out;

    float* ws = (float*)d_ws;
    float* off_buf   = ws + O_OFF;
    float* mask_buf  = ws + O_MASK;
    __hip_bfloat16* Wbf  = (__hip_bfloat16*)(ws + O_WBF);
    __hip_bfloat16* Wpk  = (__hip_bfloat16*)(ws + O_WPK);
    __hip_bfloat16* Abuf = (__hip_bfloat16*)(ws + O_A);
    __hip_bfloat16* xT   = (__hip_bfloat16*)(ws + O_XT);
    __hip_bfloat16* resT = (__hip_bfloat16*)(ws + O_RT);

    pack_kernel<<<(CK * COo + 255) / 256, 256, 0, stream>>>(reg_w, off_w, mod_w, Wbf, Wpk);

    transpose_kernel<<<2 * BB * HH * 8, 256, 0, stream>>>(x, resid, xT, resT);

    convA2_kernel<<<512, 128, 0, stream>>>(xT, resT, Wpk, off_b, mod_b,
                                           off_buf, mask_buf);

    gather_kernel<<<BB * HH * 8, 256, 0, stream>>>(xT, off_buf, mask_buf, Abuf);

    gemm_kernel<<<256, 256, 0, stream>>>(Abuf, Wbf, out);
}